// Round 1
// 182.959 us; speedup vs baseline: 1.0216x; 1.0216x over previous
//
#include <hip/hip_runtime.h>

#define CIN   256
#define COUT  256
#define NB    32
#define HIN   64
#define WIN   64
#define INV_SPATIAL (1.0f / 16384.0f)   // 1/(128*128)
#define MULT  2.0f

typedef float vfloat4 __attribute__((ext_vector_type(4)));  // clang-native, NT-load OK

// ---------------------------------------------------------------------------
// Kernel 1 (fused): blocks [0, 8192) reduce one (b,c) 64x64 x-tile to
// {Sx, Row0(h=0), Col0(w=0), X00}; blocks [8192, 8448) reduce one c-slice of
// weight to per-(c,o) {Wsum, Wr(kh=0), Wc(kw=0), W00} packed as float4.
// x is streamed once -> non-temporal loads (no L2 fill contention).
// This kernel is HBM-BW-bound at ~86% of peak: unchanged.
// ---------------------------------------------------------------------------
__global__ __launch_bounds__(256) void stats_kernel(
    const float* __restrict__ x, const float* __restrict__ w,
    float4* __restrict__ xs, float4* __restrict__ ws4)
{
    const int blk = blockIdx.x;
    const int t   = threadIdx.x;

    if (blk < NB * CIN) {
        // ---- x tile reduce ----
        const vfloat4* p = (const vfloat4*)(x + (size_t)blk * (HIN * WIN));
        float s_all = 0.f, s_r0 = 0.f, s_c0 = 0.f, x00 = 0.f;
#pragma unroll
        for (int i = 0; i < 4; ++i) {
            const int idx = t + 256 * i;                 // float4 index 0..1023
            const vfloat4 v = __builtin_nontemporal_load(p + idx);
            s_all += v.x + v.y + v.z + v.w;
            if (idx < 16)        s_r0 += v.x + v.y + v.z + v.w; // row h=0
            if ((idx & 15) == 0) s_c0 += v.x;                   // col w=0
            if (idx == 0)        x00 = v.x;
        }
#pragma unroll
        for (int off = 32; off > 0; off >>= 1) {
            s_all += __shfl_down(s_all, off);
            s_r0  += __shfl_down(s_r0,  off);
            s_c0  += __shfl_down(s_c0,  off);
        }
        __shared__ float red[4][3];
        const int wave = t >> 6, lane = t & 63;
        if (lane == 0) { red[wave][0] = s_all; red[wave][1] = s_r0; red[wave][2] = s_c0; }
        __syncthreads();
        if (t == 0) {
            float a = 0.f, r = 0.f, c = 0.f;
#pragma unroll
            for (int wv = 0; wv < 4; ++wv) { a += red[wv][0]; r += red[wv][1]; c += red[wv][2]; }
            float4 o4; o4.x = a; o4.y = r; o4.z = c; o4.w = x00;
            xs[blk] = o4;
        }
    } else {
        // ---- weight reduce: c = blk - 8192, o = t ----
        const int c = blk - NB * CIN;
        const float* p = w + ((size_t)c * COUT + t) * 9;
        const float w0 = p[0], w1 = p[1], w2 = p[2],
                    w3 = p[3], w4 = p[4], w5 = p[5],
                    w6 = p[6], w7 = p[7], w8 = p[8];
        float4 o4;
        o4.x = w0 + w1 + w2 + w3 + w4 + w5 + w6 + w7 + w8; // Wsum
        o4.y = w0 + w1 + w2;                               // Wr (kh=0)
        o4.z = w0 + w3 + w6;                               // Wc (kw=0)
        o4.w = w0;                                         // W00
        ws4[c * COUT + t] = o4;
    }
}

// ---------------------------------------------------------------------------
// Kernel 2: out[b,o] = 2*( (1/16384)*sum_c(Sx*Wsum - Row0*Wr - Col0*Wc
//                                          + X00*W00) + bias[o] )
// 256 blocks (one per CU): block = (b, 32-wide o slice). 512 threads =
// (oo 0..31, seg 0..15); each thread dots 16 c's (independent, unrolled
// L2-resident float4 loads; 512B contiguous per 32-lane group), then a
// 16-way LDS reduce. Was 64 blocks / 64 CUs -> latency-bound tail.
// ---------------------------------------------------------------------------
__global__ __launch_bounds__(512) void finalize_kernel(
    const float4* __restrict__ xs, const float4* __restrict__ ws4,
    const float* __restrict__ bias, float* __restrict__ out)
{
    const int blk  = blockIdx.x;          // 256 blocks
    const int b    = blk >> 3;            // 0..31
    const int part = blk & 7;             // 0..7 -> o slice
    const int t    = threadIdx.x;         // 0..511
    const int oo   = t & 31;
    const int seg  = t >> 5;              // 0..15
    const int o    = part * 32 + oo;

    __shared__ float4 sx[CIN];            // 4 KiB
    __shared__ float  red[16][32];        // 2 KiB
    if (t < CIN) sx[t] = xs[b * CIN + t];
    __syncthreads();

    float acc = 0.f;
    const int c0 = seg * 16;
#pragma unroll
    for (int i = 0; i < 16; ++i) {
        const int c = c0 + i;
        const float4 s  = sx[c];                          // wave-uniform broadcast
        const float4 wv = ws4[c * COUT + o];              // coalesced, L2-hit
        acc += s.x * wv.x - s.y * wv.y - s.z * wv.z + s.w * wv.w;
    }
    red[seg][oo] = acc;
    __syncthreads();
    if (t < 32) {
        float a = 0.f;
#pragma unroll
        for (int sg = 0; sg < 16; ++sg) a += red[sg][t];  // stride-32 rows, no conflict
        const int og = part * 32 + t;
        out[b * COUT + og] = MULT * (a * INV_SPATIAL + bias[og]);
    }
}

// ---------------------------------------------------------------------------
extern "C" void kernel_launch(void* const* d_in, const int* in_sizes, int n_in,
                              void* d_out, int out_size, void* d_ws, size_t ws_size,
                              hipStream_t stream)
{
    const float* x      = (const float*)d_in[0];   // (32,256,64,64)
    const float* weight = (const float*)d_in[1];   // (256,256,3,3)
    const float* bias   = (const float*)d_in[2];   // (256,)
    float* out = (float*)d_out;                    // (32,256,1,1)

    float4* xs  = (float4*)d_ws;                   // 8192 float4 = 128 KiB
    float4* ws4 = xs + (size_t)NB * CIN;           // 65536 float4 = 1 MiB

    stats_kernel<<<NB * CIN + CIN, 256, 0, stream>>>(x, weight, xs, ws4);
    finalize_kernel<<<NB * 8, 512, 0, stream>>>(xs, ws4, bias, out);
}